// Round 1
// baseline (1596.965 us; speedup 1.0000x reference)
//
#include <hip/hip_runtime.h>
#include <cstdint>
#include <cstddef>

// ---------------------------------------------------------------------------
// Pointer-network decoder: B=128 batches decode T=32 steps over N=512 nodes.
// Key insight: the whole decode is independent per batch element -> one fused
// kernel, 1 block per batch, all recurrent state in LDS.
// Sampling must reproduce jax.random.categorical bit-exactly (threefry2x32,
// partitionable/fold-like semantics = modern JAX default).
// ---------------------------------------------------------------------------

#define JAX_PARTITIONABLE 1   // flip to 0 if indices mismatch (legacy jax PRNG)

constexpr int B = 128, N = 512, H = 128, T = 32;
constexpr int G4 = 4 * H;  // 512
constexpr float TINYF = 1.17549435e-38f;  // np.finfo(float32).tiny

// ---- JAX threefry2x32 block cipher (20 rounds) ----------------------------
__host__ __device__ inline uint32_t rotl32(uint32_t v, int d) {
  return (v << d) | (v >> (32 - d));
}

__host__ __device__ inline void tf2x32(uint32_t k0, uint32_t k1,
                                       uint32_t x0, uint32_t x1,
                                       uint32_t& o0, uint32_t& o1) {
  uint32_t ks2 = k0 ^ k1 ^ 0x1BD11BDAu;
  x0 += k0; x1 += k1;
#define TF_R(r) x0 += x1; x1 = rotl32(x1, (r)); x1 ^= x0;
  TF_R(13) TF_R(15) TF_R(26) TF_R(6)
  x0 += k1; x1 += ks2 + 1u;
  TF_R(17) TF_R(29) TF_R(16) TF_R(24)
  x0 += ks2; x1 += k0 + 2u;
  TF_R(13) TF_R(15) TF_R(26) TF_R(6)
  x0 += k0; x1 += k1 + 3u;
  TF_R(17) TF_R(29) TF_R(16) TF_R(24)
  x0 += k1; x1 += ks2 + 4u;
  TF_R(13) TF_R(15) TF_R(26) TF_R(6)
  x0 += ks2; x1 += k0 + 5u;
#undef TF_R
  o0 = x0; o1 = x1;
}

struct KeyArgs { uint32_t k[2 * T]; };  // per-step subkeys, 256 B by value

// Host-side key chain: key0 = jax.random.key(42) = (0,42);
// each step: key, sub = jax.random.split(key).
static KeyArgs make_subkeys() {
  KeyArgs ka;
  uint32_t k0 = 0u, k1 = 42u;
  for (int t = 0; t < T; ++t) {
#if JAX_PARTITIONABLE
    // fold-like split: keys[i] = E_key(0, i), both output words
    uint32_t n0, n1, s0, s1;
    tf2x32(k0, k1, 0u, 0u, n0, n1);
    tf2x32(k0, k1, 0u, 1u, s0, s1);
    ka.k[2 * t] = s0; ka.k[2 * t + 1] = s1;
    k0 = n0; k1 = n1;
#else
    // original split: counts [0,1,2,3] -> pairs (0,2),(1,3);
    // out = concat(word0s, word1s).reshape(2,2)
    uint32_t a0, a1, b0, b1;
    tf2x32(k0, k1, 0u, 2u, a0, a1);
    tf2x32(k0, k1, 1u, 3u, b0, b1);
    ka.k[2 * t] = a1; ka.k[2 * t + 1] = b1;  // sub = row 1
    k0 = a0; k1 = b0;                        // new key = row 0
#endif
  }
  return ka;
}

// 32-bit random draw i of 65536 for this step's subkey
__device__ inline uint32_t gumbel_bits(uint32_t sk0, uint32_t sk1, int i) {
#if JAX_PARTITIONABLE
  uint32_t o0, o1;
  tf2x32(sk0, sk1, 0u, (uint32_t)i, o0, o1);
  return o0 ^ o1;
#else
  uint32_t o0, o1;
  if (i < 32768) { tf2x32(sk0, sk1, (uint32_t)i, (uint32_t)(i + 32768), o0, o1); return o0; }
  tf2x32(sk0, sk1, (uint32_t)(i - 32768), (uint32_t)i, o0, o1); return o1;
#endif
}

// fast tanh for the score hot loop; abs err ~2e-7 (clamp avoids inf/inf NaN)
__device__ inline float fast_tanh(float x) {
  float cx = fminf(9.0f, fmaxf(-9.0f, x));
  float t = __expf(2.0f * cx);
  return (t - 1.0f) * __builtin_amdgcn_rcpf(t + 1.0f);
}

// ---- setup kernel 1: transpose weights for coalesced access ---------------
__global__ void k_transpose(const float* __restrict__ Wih, const float* __restrict__ Whh,
                            const float* __restrict__ W2, const float* __restrict__ W1,
                            float* __restrict__ WihT, float* __restrict__ WhhT,
                            float* __restrict__ W2T, float* __restrict__ W1T) {
  int i = blockIdx.x * blockDim.x + threadIdx.x;
  if (i < H * G4) {
    int h = i >> 9, j = i & (G4 - 1);
    WihT[i] = Wih[j * H + h];
  } else if (i < 2 * H * G4) {
    int q = i - H * G4; int h = q >> 9, j = q & (G4 - 1);
    WhhT[q] = Whh[j * H + h];
  } else if (i < 2 * H * G4 + H * H) {
    int q = i - 2 * H * G4; int h = q >> 7, k = q & (H - 1);
    W2T[q] = W2[k * H + h];
  } else if (i < 2 * H * G4 + 2 * H * H) {
    int q = i - 2 * H * G4 - H * H; int h = q >> 7, k = q & (H - 1);
    W1T[q] = W1[k * H + h];
  }
}

// ---- setup kernel 2: enc_trans[b,n,k] = sum_h enc[b,n,h] * W1[k,h] --------
// 16 encoder rows per block staged in LDS; 256 threads = 128 k x 2 n-groups.
__global__ __launch_bounds__(256) void k_enc_trans(const float* __restrict__ enc,
                                                   const float* __restrict__ W1T,
                                                   float* __restrict__ encT) {
  __shared__ __align__(16) float es[16 * 128];  // 8 KB
  int blk = blockIdx.x;
  int b = blk >> 5;               // 32 blocks per batch
  int n0 = (blk & 31) << 4;       // 16 rows
  const float* src = enc + ((size_t)b * N + n0) * H;
  for (int i = threadIdx.x; i < 16 * 128; i += 256) es[i] = src[i];
  __syncthreads();
  int k = threadIdx.x & 127, ng = threadIdx.x >> 7;
  float acc[8] = {0.f, 0.f, 0.f, 0.f, 0.f, 0.f, 0.f, 0.f};
  for (int h = 0; h < H; h += 4) {
    float w0 = W1T[(h + 0) * H + k];   // coalesced (lanes = consecutive k)
    float w1 = W1T[(h + 1) * H + k];
    float w2 = W1T[(h + 2) * H + k];
    float w3 = W1T[(h + 3) * H + k];
#pragma unroll
    for (int j = 0; j < 8; ++j) {
      const float4 e = *(const float4*)&es[(ng * 8 + j) * 128 + h];  // broadcast
      acc[j] += w0 * e.x + w1 * e.y + w2 * e.z + w3 * e.w;
    }
  }
#pragma unroll
  for (int j = 0; j < 8; ++j)
    encT[((size_t)b * N + n0 + ng * 8 + j) * H + k] = acc[j];
}

// ---- main fused decoder: 1 block per batch element, 512 threads -----------
__global__ __launch_bounds__(512) void k_decode(
    const float* __restrict__ enc, const float* __restrict__ encT,
    const float* __restrict__ WihT, const float* __restrict__ WhhT,
    const float* __restrict__ W2T,
    const float* __restrict__ bih, const float* __restrict__ bhh,
    const float* __restrict__ v,
    KeyArgs keys, float* __restrict__ out) {
  __shared__ __align__(16) float xs[H];   // dec_input
  __shared__ __align__(16) float hs[H];   // hx
  __shared__ __align__(16) float cs[H];   // cx
  __shared__ __align__(16) float dt[H];   // dec_trans = hx @ W2^T
  __shared__ __align__(16) float vv[H];
  __shared__ float gates[G4];
  __shared__ float sc[N];                 // scores (masked after phase 5)
  __shared__ int msk[N];
  __shared__ float wr_z[8], wr_m[8], wr_s[8];
  __shared__ int wr_i[8];
  __shared__ float s_smax;
  __shared__ int s_idx;

  const int tid = threadIdx.x;
  const int b = blockIdx.x;
  const int lane = tid & 63;
  const int wave = tid >> 6;

  // init: dec_input = mean_n enc[b,n,:], h = c = 0, mask = 0
  if (tid < H) {
    float s = 0.f;
    const float* p = enc + (size_t)b * N * H + tid;
#pragma unroll 8
    for (int n = 0; n < N; ++n) s += p[(size_t)n * H];  // coalesced across tid
    xs[tid] = s * (1.0f / N);
    hs[tid] = 0.f;
    cs[tid] = 0.f;
    vv[tid] = v[tid];
  }
  for (int n = tid; n < N; n += 512) msk[n] = 0;
  __syncthreads();

  const float2 vvl = ((const float2*)vv)[lane];  // lane covers h = 2*lane, 2*lane+1

  for (int t = 0; t < T; ++t) {
    // --- Phase 1: LSTM gates[j] = b + W_ih[j,:]·x + W_hh[j,:]·h  (j = tid) --
    {
      float a = bih[tid] + bhh[tid];
      const float* wi = WihT + tid;  // WihT[h][j], lanes = consecutive j
      const float* wh = WhhT + tid;
#pragma unroll 8
      for (int h = 0; h < H; ++h)
        a += wi[h * G4] * xs[h] + wh[h * G4] * hs[h];
      gates[tid] = a;
    }
    __syncthreads();
    // --- Phase 2: cell update (torch gate order i,f,g,o) --------------------
    if (tid < H) {
      float gi = 1.0f / (1.0f + expf(-gates[tid]));
      float gf = 1.0f / (1.0f + expf(-gates[H + tid]));
      float gg = tanhf(gates[2 * H + tid]);
      float go = 1.0f / (1.0f + expf(-gates[3 * H + tid]));
      float c = gf * cs[tid] + gi * gg;
      cs[tid] = c;
      hs[tid] = go * tanhf(c);
    }
    __syncthreads();
    // --- Phase 3: dec_trans[k] = W2[k,:]·h ---------------------------------
    if (tid < H) {
      float a = 0.f;
      const float* w2 = W2T + tid;
#pragma unroll 8
      for (int h = 0; h < H; ++h) a += w2[h * H] * hs[h];
      dt[tid] = a;
    }
    __syncthreads();
    // --- Phase 4: scores[n] = v · tanh(encT[b,n,:] + dt) -------------------
    // wave w owns rows [w*64, w*64+64); lanes split the 128-dim h as float2
    {
      const float2 dv = ((const float2*)dt)[lane];
      const float2* ebase = (const float2*)(encT + ((size_t)b * N + wave * 64) * H);
#pragma unroll 2
      for (int i = 0; i < 64; ++i) {
        float2 e = ebase[i * 64 + lane];  // coalesced 512B per wave
        float p = vvl.x * fast_tanh(e.x + dv.x) + vvl.y * fast_tanh(e.y + dv.y);
        p += __shfl_xor(p, 32); p += __shfl_xor(p, 16); p += __shfl_xor(p, 8);
        p += __shfl_xor(p, 4);  p += __shfl_xor(p, 2);  p += __shfl_xor(p, 1);
        if (lane == 0) sc[wave * 64 + i] = p;
      }
    }
    __syncthreads();
    // --- Phase 5: mask, gumbel, per-wave argmax + score max ----------------
    {
      float s = msk[tid] ? -INFINITY : sc[tid];
      sc[tid] = s;  // keep masked score for softmax
      uint32_t bits = gumbel_bits(keys.k[2 * t], keys.k[2 * t + 1], b * N + tid);
      // XLA uniform(minval=tiny, maxval=1): bits->[1,2)->-1, *1.0 + tiny, max
      float f = __uint_as_float((bits >> 9) | 0x3f800000u) - 1.0f;
      float u = fmaxf(TINYF, f + TINYF);
      float g = -logf(-logf(u));  // accurate logf: hw log2 too sloppy near u~1
      float z = s + g;
      int zi = tid;
      float m = s;
#pragma unroll
      for (int d = 32; d >= 1; d >>= 1) {
        float oz = __shfl_xor(z, d);
        int oi = __shfl_xor(zi, d);
        float om = __shfl_xor(m, d);
        if (oz > z || (oz == z && oi < zi)) { z = oz; zi = oi; }  // first-idx ties
        m = fmaxf(m, om);
      }
      if (lane == 0) { wr_z[wave] = z; wr_i[wave] = zi; wr_m[wave] = m; }
    }
    __syncthreads();
    if (tid == 0) {
      float bz = wr_z[0]; int bi = wr_i[0]; float bm = wr_m[0];
#pragma unroll
      for (int w = 1; w < 8; ++w) {
        if (wr_z[w] > bz || (wr_z[w] == bz && wr_i[w] < bi)) { bz = wr_z[w]; bi = wr_i[w]; }
        bm = fmaxf(bm, wr_m[w]);
      }
      s_idx = bi; s_smax = bm;
    }
    __syncthreads();
    // --- Phase 6: softmax denom + outputs ----------------------------------
    {
      float e = expf(sc[tid] - s_smax);  // masked: exp(-inf) = 0
#pragma unroll
      for (int d = 32; d >= 1; d >>= 1) e += __shfl_xor(e, d);
      if (lane == 0) wr_s[wave] = e;
    }
    __syncthreads();
    if (tid == 0) {
      float sum = wr_s[0] + wr_s[1] + wr_s[2] + wr_s[3]
                + wr_s[4] + wr_s[5] + wr_s[6] + wr_s[7];
      int idx = s_idx;
      float p = expf(sc[idx] - s_smax) / sum;
      out[(size_t)b * T + t] = (float)idx;                       // tours [B,T]
      out[(size_t)B * T + (size_t)b * T + t] = logf(p + 1e-9f);  // log_probs
      msk[idx] = 1;
    }
    __syncthreads();
    // --- Phase 7: dec_input = enc[b, idx, :] -------------------------------
    if (tid < H) xs[tid] = enc[((size_t)b * N + s_idx) * H + tid];
    __syncthreads();
  }
}

// ---------------------------------------------------------------------------
extern "C" void kernel_launch(void* const* d_in, const int* in_sizes, int n_in,
                              void* d_out, int out_size, void* d_ws, size_t ws_size,
                              hipStream_t stream) {
  (void)in_sizes; (void)n_in; (void)out_size; (void)ws_size;
  const float* enc = (const float*)d_in[0];
  const float* Wih = (const float*)d_in[1];
  const float* Whh = (const float*)d_in[2];
  const float* bih = (const float*)d_in[3];
  const float* bhh = (const float*)d_in[4];
  const float* W1  = (const float*)d_in[5];
  const float* W2  = (const float*)d_in[6];
  const float* v   = (const float*)d_in[7];
  float* out = (float*)d_out;
  float* ws = (float*)d_ws;

  // ws layout (floats): WihT 65536 | WhhT 65536 | W2T 16384 | W1T 16384 | encT 8388608
  float* WihT = ws;
  float* WhhT = ws + 65536;
  float* W2T  = ws + 131072;
  float* W1T  = ws + 147456;
  float* encT = ws + 163840;   // total ~34.2 MB

  KeyArgs keys = make_subkeys();  // pure host arithmetic: capture-safe, deterministic

  k_transpose<<<640, 256, 0, stream>>>(Wih, Whh, W2, W1, WihT, WhhT, W2T, W1T);
  k_enc_trans<<<B * N / 16, 256, 0, stream>>>(enc, W1T, encT);
  k_decode<<<B, 512, 0, stream>>>(enc, encT, WihT, WhhT, W2T, bih, bhh, v, keys, out);
}

// Round 2
// 615.526 us; speedup vs baseline: 2.5945x; 2.5945x over previous
//
#include <hip/hip_runtime.h>
#include <cstdint>
#include <cstddef>

// ---------------------------------------------------------------------------
// Pointer-network decoder: B=128 batches decode T=32 steps over N=512 nodes.
// One block per batch (sequential dependence across steps), 1024 threads.
// Round 2: enc_trans stored [b][k][n] -> score phase is a shuffle-free,
// fully-pipelineable SGEMV (thread n owns score n); split-K over two
// 512-thread halves for LSTM gates and scores; 16 waves/CU.
// Sampling reproduces jax.random.categorical bit-exactly (threefry2x32,
// partitionable semantics) -- verified absmax 0.0 in round 1.
// ---------------------------------------------------------------------------

constexpr int B = 128, N = 512, H = 128, T = 32;
constexpr int G4 = 4 * H;  // 512
constexpr float TINYF = 1.17549435e-38f;  // np.finfo(float32).tiny

// ---- JAX threefry2x32 block cipher (20 rounds) ----------------------------
__host__ __device__ inline uint32_t rotl32(uint32_t v, int d) {
  return (v << d) | (v >> (32 - d));
}

__host__ __device__ inline void tf2x32(uint32_t k0, uint32_t k1,
                                       uint32_t x0, uint32_t x1,
                                       uint32_t& o0, uint32_t& o1) {
  uint32_t ks2 = k0 ^ k1 ^ 0x1BD11BDAu;
  x0 += k0; x1 += k1;
#define TF_R(r) x0 += x1; x1 = rotl32(x1, (r)); x1 ^= x0;
  TF_R(13) TF_R(15) TF_R(26) TF_R(6)
  x0 += k1; x1 += ks2 + 1u;
  TF_R(17) TF_R(29) TF_R(16) TF_R(24)
  x0 += ks2; x1 += k0 + 2u;
  TF_R(13) TF_R(15) TF_R(26) TF_R(6)
  x0 += k0; x1 += k1 + 3u;
  TF_R(17) TF_R(29) TF_R(16) TF_R(24)
  x0 += k1; x1 += ks2 + 4u;
  TF_R(13) TF_R(15) TF_R(26) TF_R(6)
  x0 += ks2; x1 += k0 + 5u;
#undef TF_R
  o0 = x0; o1 = x1;
}

struct KeyArgs { uint32_t k[2 * T]; };  // per-step subkeys, 256 B by value

// Host-side key chain (partitionable split): key0 = (0,42);
// new_key = E_key(0,0), sub = E_key(0,1).
static KeyArgs make_subkeys() {
  KeyArgs ka;
  uint32_t k0 = 0u, k1 = 42u;
  for (int t = 0; t < T; ++t) {
    uint32_t n0, n1, s0, s1;
    tf2x32(k0, k1, 0u, 0u, n0, n1);
    tf2x32(k0, k1, 0u, 1u, s0, s1);
    ka.k[2 * t] = s0; ka.k[2 * t + 1] = s1;
    k0 = n0; k1 = n1;
  }
  return ka;
}

// 32-bit draw i (of 65536) for this step's subkey: w0^w1 of E_sub(0, i)
__device__ inline uint32_t gumbel_bits(uint32_t sk0, uint32_t sk1, int i) {
  uint32_t o0, o1;
  tf2x32(sk0, sk1, 0u, (uint32_t)i, o0, o1);
  return o0 ^ o1;
}

// fast tanh for the score hot loop; abs err ~2e-7 (clamp avoids inf/inf NaN)
__device__ inline float fast_tanh(float x) {
  float cx = fminf(9.0f, fmaxf(-9.0f, x));
  float t = __expf(2.0f * cx);
  return (t - 1.0f) * __builtin_amdgcn_rcpf(t + 1.0f);
}

// ---- setup kernel 1: transpose weights for coalesced access ---------------
__global__ void k_transpose(const float* __restrict__ Wih, const float* __restrict__ Whh,
                            const float* __restrict__ W2, const float* __restrict__ W1,
                            float* __restrict__ WihT, float* __restrict__ WhhT,
                            float* __restrict__ W2T, float* __restrict__ W1T) {
  int i = blockIdx.x * blockDim.x + threadIdx.x;
  if (i < H * G4) {
    int h = i >> 9, j = i & (G4 - 1);
    WihT[i] = Wih[j * H + h];
  } else if (i < 2 * H * G4) {
    int q = i - H * G4; int h = q >> 9, j = q & (G4 - 1);
    WhhT[q] = Whh[j * H + h];
  } else if (i < 2 * H * G4 + H * H) {
    int q = i - 2 * H * G4; int h = q >> 7, k = q & (H - 1);
    W2T[q] = W2[k * H + h];
  } else if (i < 2 * H * G4 + 2 * H * H) {
    int q = i - 2 * H * G4 - H * H; int h = q >> 7, k = q & (H - 1);
    W1T[q] = W1[k * H + h];
  }
}

// ---- setup kernel 2: encT2[b,k,n] = sum_h enc[b,n,h] * W1[k,h] ------------
// (k-major output for the decode score SGEMV). 16 enc rows staged in LDS;
// 256 threads = 128 k x 2 n-groups; per-thread 8 consecutive n -> 2x float4.
__global__ __launch_bounds__(256) void k_enc_trans(const float* __restrict__ enc,
                                                   const float* __restrict__ W1T,
                                                   float* __restrict__ encT2) {
  __shared__ __align__(16) float es[16 * 128];  // 8 KB
  int blk = blockIdx.x;
  int b = blk >> 5;               // 32 blocks per batch
  int n0 = (blk & 31) << 4;       // 16 rows
  const float* src = enc + ((size_t)b * N + n0) * H;
  for (int i = threadIdx.x; i < 16 * 128; i += 256) es[i] = src[i];
  __syncthreads();
  int k = threadIdx.x & 127, ng = threadIdx.x >> 7;
  float acc[8] = {0.f, 0.f, 0.f, 0.f, 0.f, 0.f, 0.f, 0.f};
  for (int h = 0; h < H; h += 4) {
    float w0 = W1T[(h + 0) * H + k];   // coalesced (lanes = consecutive k)
    float w1 = W1T[(h + 1) * H + k];
    float w2 = W1T[(h + 2) * H + k];
    float w3 = W1T[(h + 3) * H + k];
#pragma unroll
    for (int j = 0; j < 8; ++j) {
      const float4 e = *(const float4*)&es[(ng * 8 + j) * 128 + h];  // broadcast
      acc[j] += w0 * e.x + w1 * e.y + w2 * e.z + w3 * e.w;
    }
  }
  float* dst = encT2 + (size_t)b * H * N + (size_t)k * N + n0 + ng * 8;
  ((float4*)dst)[0] = make_float4(acc[0], acc[1], acc[2], acc[3]);
  ((float4*)dst)[1] = make_float4(acc[4], acc[5], acc[6], acc[7]);
}

// ---- main fused decoder: 1 block per batch, 1024 threads (16 waves) -------
__global__ __launch_bounds__(1024) void k_decode(
    const float* __restrict__ enc, const float* __restrict__ encT2,
    const float* __restrict__ WihT, const float* __restrict__ WhhT,
    const float* __restrict__ W2T,
    const float* __restrict__ bih, const float* __restrict__ bhh,
    const float* __restrict__ v,
    KeyArgs keys, float* __restrict__ out) {
  __shared__ __align__(16) float xs[H];     // dec_input
  __shared__ __align__(16) float hs[H];     // hx
  __shared__ __align__(16) float cs[H];     // cx
  __shared__ __align__(16) float dt[H];     // dec_trans = hx @ W2^T
  __shared__ __align__(16) float vv[H];
  __shared__ __align__(16) float bsum[G4];  // b_ih + b_hh
  __shared__ float pg[2][G4];               // gate partials (split-K halves)
  __shared__ float ps[2][N];                // score partials
  __shared__ float pdt[4][H];               // dt partials (and init-mean partials)
  __shared__ float sc[N];                   // masked scores for softmax
  __shared__ float wr_z[8], wr_m[8], wr_s[8];
  __shared__ int wr_i[8];
  __shared__ float s_smax;
  __shared__ int s_idx;

  const int tid = threadIdx.x;
  const int b = blockIdx.x;
  const int lane = tid & 63;
  const int wave = tid >> 6;
  const int half = tid >> 9;     // 0/1: split-K half
  const int id = tid & 511;

  // ---- init: dec_input = mean_n enc[b,n,:]; h = c = 0 ----
  if (tid < 512) {
    int h = tid & 127, part = tid >> 7;
    float s = 0.f;
    const float* p = enc + ((size_t)b * N + part * 128) * H + h;
#pragma unroll 8
    for (int n = 0; n < 128; ++n) s += p[(size_t)n * H];  // coalesced across h
    pdt[part][h] = s;
    bsum[tid] = bih[tid] + bhh[tid];
  }
  if (tid < 128) { hs[tid] = 0.f; cs[tid] = 0.f; vv[tid] = v[tid]; }
  __syncthreads();
  if (tid < 128)
    xs[tid] = (pdt[0][tid] + pdt[1][tid] + pdt[2][tid] + pdt[3][tid]) * (1.0f / N);
  bool masked = false;  // thread id owns node id (tid<512)
  __syncthreads();

  for (int t = 0; t < T; ++t) {
    // --- P1: gate partials: j = id, h-range = half*64..+63 ------------------
    {
      const float* wi = WihT + (size_t)(half * 64) * G4 + id;
      const float* wh = WhhT + (size_t)(half * 64) * G4 + id;
      const int hb = half * 64;
      float a0 = 0.f, a1 = 0.f;
#pragma unroll 8
      for (int h = 0; h < 64; ++h) {
        a0 += wi[h * G4] * xs[hb + h];
        a1 += wh[h * G4] * hs[hb + h];
      }
      pg[half][id] = a0 + a1;
    }
    __syncthreads();
    // --- P2: cell update (torch gate order i,f,g,o) -------------------------
    if (tid < 128) {
      float gi = pg[0][tid] + pg[1][tid] + bsum[tid];
      float gf = pg[0][H + tid] + pg[1][H + tid] + bsum[H + tid];
      float gg = pg[0][2 * H + tid] + pg[1][2 * H + tid] + bsum[2 * H + tid];
      float go = pg[0][3 * H + tid] + pg[1][3 * H + tid] + bsum[3 * H + tid];
      gi = 1.0f / (1.0f + expf(-gi));
      gf = 1.0f / (1.0f + expf(-gf));
      gg = tanhf(gg);
      go = 1.0f / (1.0f + expf(-go));
      float c = gf * cs[tid] + gi * gg;
      cs[tid] = c;
      hs[tid] = go * tanhf(c);
    }
    __syncthreads();
    // --- P3: dt partials: k = tid&127, 32 h each ----------------------------
    if (tid < 512) {
      int k = tid & 127, part = tid >> 7;
      const float* w2 = W2T + (size_t)(part * 32) * H + k;
      const int hb = part * 32;
      float a = 0.f;
#pragma unroll 8
      for (int h = 0; h < 32; ++h) a += w2[h * H] * hs[hb + h];
      pdt[part][k] = a;
    }
    __syncthreads();
    if (tid < 128) dt[tid] = pdt[0][tid] + pdt[1][tid] + pdt[2][tid] + pdt[3][tid];
    __syncthreads();
    // --- P4: score partials: thread n = id, k-range = half*64..+63 ----------
    // encT2[b][k][n]: coalesced across n; dt/vv broadcast from LDS; no shuffles
    {
      const int kb = half * 64;
      const float* ep = encT2 + (size_t)b * (H * N) + (size_t)kb * N + id;
      float a0 = 0.f, a1 = 0.f;
#pragma unroll 8
      for (int kk = 0; kk < 64; kk += 2) {
        float e0 = ep[(size_t)kk * N];
        float e1 = ep[(size_t)(kk + 1) * N];
        a0 += vv[kb + kk] * fast_tanh(e0 + dt[kb + kk]);
        a1 += vv[kb + kk + 1] * fast_tanh(e1 + dt[kb + kk + 1]);
      }
      ps[half][id] = a0 + a1;
    }
    __syncthreads();
    // --- P5a: mask, gumbel, per-wave argmax + score max (waves 0..7) --------
    if (tid < 512) {
      float s = masked ? -INFINITY : (ps[0][tid] + ps[1][tid]);
      sc[tid] = s;
      uint32_t bits = gumbel_bits(keys.k[2 * t], keys.k[2 * t + 1], b * N + tid);
      // XLA uniform(minval=tiny, maxval=1): bits->[1,2)->-1, +tiny, max
      float f = __uint_as_float((bits >> 9) | 0x3f800000u) - 1.0f;
      float u = fmaxf(TINYF, f + TINYF);
      float g = -logf(-logf(u));  // accurate logf (hw log2 too sloppy near u~1)
      float z = s + g;
      int zi = tid;
      float m = s;
#pragma unroll
      for (int d = 32; d >= 1; d >>= 1) {
        float oz = __shfl_xor(z, d);
        int oi = __shfl_xor(zi, d);
        float om = __shfl_xor(m, d);
        if (oz > z || (oz == z && oi < zi)) { z = oz; zi = oi; }  // first-idx ties
        m = fmaxf(m, om);
      }
      if (lane == 0) { wr_z[wave] = z; wr_i[wave] = zi; wr_m[wave] = m; }
    }
    __syncthreads();
    // --- P5b: final argmax + max over the 8 waves ---------------------------
    if (tid == 0) {
      float bz = wr_z[0]; int bi = wr_i[0]; float bm = wr_m[0];
#pragma unroll
      for (int w = 1; w < 8; ++w) {
        if (wr_z[w] > bz || (wr_z[w] == bz && wr_i[w] < bi)) { bz = wr_z[w]; bi = wr_i[w]; }
        bm = fmaxf(bm, wr_m[w]);
      }
      s_idx = bi; s_smax = bm;
    }
    __syncthreads();
    // --- P6: softmax denom; mask update; next dec_input ---------------------
    if (tid < 512) {
      float e = expf(sc[tid] - s_smax);  // masked: exp(-inf) = 0
#pragma unroll
      for (int d = 32; d >= 1; d >>= 1) e += __shfl_xor(e, d);
      if (lane == 0) wr_s[wave] = e;
      if (tid == s_idx) masked = true;
    } else if (tid < 640) {
      xs[tid - 512] = enc[((size_t)b * N + s_idx) * H + (tid - 512)];
    }
    __syncthreads();
    // --- P6b: outputs (no barrier needed: writes global only) ---------------
    if (tid == 0) {
      float sum = wr_s[0] + wr_s[1] + wr_s[2] + wr_s[3]
                + wr_s[4] + wr_s[5] + wr_s[6] + wr_s[7];
      float p = expf(sc[s_idx] - s_smax) / sum;
      out[(size_t)b * T + t] = (float)s_idx;                       // tours [B,T]
      out[(size_t)B * T + (size_t)b * T + t] = logf(p + 1e-9f);    // log_probs
    }
    __syncthreads();
  }
}

// ---------------------------------------------------------------------------
extern "C" void kernel_launch(void* const* d_in, const int* in_sizes, int n_in,
                              void* d_out, int out_size, void* d_ws, size_t ws_size,
                              hipStream_t stream) {
  (void)in_sizes; (void)n_in; (void)out_size; (void)ws_size;
  const float* enc = (const float*)d_in[0];
  const float* Wih = (const float*)d_in[1];
  const float* Whh = (const float*)d_in[2];
  const float* bih = (const float*)d_in[3];
  const float* bhh = (const float*)d_in[4];
  const float* W1  = (const float*)d_in[5];
  const float* W2  = (const float*)d_in[6];
  const float* v   = (const float*)d_in[7];
  float* out = (float*)d_out;
  float* ws = (float*)d_ws;

  // ws layout (floats): WihT 65536 | WhhT 65536 | W2T 16384 | W1T 16384 | encT2 8388608
  float* WihT  = ws;
  float* WhhT  = ws + 65536;
  float* W2T   = ws + 131072;
  float* W1T   = ws + 147456;
  float* encT2 = ws + 163840;   // [b][k][n], ~33.5 MB

  KeyArgs keys = make_subkeys();  // pure host arithmetic: capture-safe

  k_transpose<<<640, 256, 0, stream>>>(Wih, Whh, W2, W1, WihT, WhhT, W2T, W1T);
  k_enc_trans<<<B * N / 16, 256, 0, stream>>>(enc, W1T, encT2);
  k_decode<<<B, 1024, 0, stream>>>(enc, encT2, WihT, WhhT, W2T, bih, bhh, v, keys, out);
}